// Round 6
// baseline (548.708 us; speedup 1.0000x reference)
//
#include <hip/hip_runtime.h>
#include <hip/hip_fp16.h>

#define BB 4
#define NN 256
#define CC 256
#define HH 96
#define WW 128
#define P0 (HH*WW)        // 12288
#define TOTPOS 16320      // 12288 + 3072 + 768 + 192 = 255*64

typedef _Float16 f16x4 __attribute__((ext_vector_type(4)));
typedef _Float16 f16x8 __attribute__((ext_vector_type(8)));
typedef float    f32x4 __attribute__((ext_vector_type(4)));

// -------------------- K1: normalize q rows -> f16 --------------------
__global__ __launch_bounds__(256) void k_qnorm(const float* __restrict__ q,
                                               _Float16* __restrict__ qn16) {
    int wid = blockIdx.x * 4 + (threadIdx.x >> 6);   // (b*N+n)
    int lane = threadIdx.x & 63;
    const float4* src = (const float4*)(q + (size_t)wid * CC);
    float4 v = src[lane];
    float ss = v.x*v.x + v.y*v.y + v.z*v.z + v.w*v.w;
    #pragma unroll
    for (int off = 32; off > 0; off >>= 1) ss += __shfl_xor(ss, off, 64);
    float inv = 1.0f / fmaxf(sqrtf(ss), 1e-12f);
    f16x4 o;
    o[0] = (_Float16)(v.x*inv); o[1] = (_Float16)(v.y*inv);
    o[2] = (_Float16)(v.z*inv); o[3] = (_Float16)(v.w*inv);
    *(f16x4*)(qn16 + (size_t)wid * CC + lane * 4) = o;
}

// -------------------- K2: pool + channel-normalize -> f16 [b][p][c] --------------------
__global__ __launch_bounds__(256) void k_pool_norm(const float* __restrict__ f,
                                                   _Float16* __restrict__ flnT) {
    int b = blockIdx.y;
    int gp = blockIdx.x;
    int lvl, pos;
    if (gp < 12288)      { lvl = 0; pos = gp; }
    else if (gp < 15360) { lvl = 1; pos = gp - 12288; }
    else if (gp < 16128) { lvl = 2; pos = gp - 15360; }
    else                 { lvl = 3; pos = gp - 16128; }
    int k = 1 << lvl;
    int wl = WW >> lvl;
    int py = pos / wl, px = pos - py * wl;
    int c = threadIdx.x;
    int iy0 = py * k, ix0 = px * k;
    float sum = 0.f;
    for (int dy = 0; dy < k; ++dy)
        for (int dx = 0; dx < k; ++dx) {
            int ip = (iy0 + dy) * WW + ix0 + dx;
            sum += f[((size_t)b * P0 + ip) * CC + c];
        }
    float val = sum * (1.0f / (float)(k * k));
    float ss = val * val;
    #pragma unroll
    for (int off = 32; off > 0; off >>= 1) ss += __shfl_xor(ss, off, 64);
    __shared__ float red[4];
    __shared__ float s_inv;
    if ((threadIdx.x & 63) == 0) red[threadIdx.x >> 6] = ss;
    __syncthreads();
    if (threadIdx.x == 0) {
        float t = red[0] + red[1] + red[2] + red[3];
        s_inv = 1.0f / fmaxf(sqrtf(t), 1e-12f);
    }
    __syncthreads();
    flnT[((size_t)b * TOTPOS + gp) * CC + c] = (_Float16)(val * s_inv);
}

// -------------------- K3: MFMA GEMM (unchanged, proven) --------------------
__global__ __launch_bounds__(256, 4) void k_gemm(const _Float16* __restrict__ qn16,
                                                 const _Float16* __restrict__ flnT,
                                                 float* __restrict__ cws) {
    int b = blockIdx.z;
    int wv = threadIdx.x >> 6, lane = threadIdx.x & 63;
    int m0 = blockIdx.y * 64 + (wv >> 1) * 32;
    int p0 = blockIdx.x * 64 + (wv & 1) * 32;
    int r = lane & 15, og = lane >> 4;

    const f16x8* A0p = (const f16x8*)(qn16 + ((size_t)(b * NN + m0 + r)) * CC) + og;
    const f16x8* A1p = (const f16x8*)(qn16 + ((size_t)(b * NN + m0 + 16 + r)) * CC) + og;
    const f16x8* B0p = (const f16x8*)(flnT + ((size_t)b * TOTPOS + p0 + r) * CC) + og;
    const f16x8* B1p = (const f16x8*)(flnT + ((size_t)b * TOTPOS + p0 + 16 + r) * CC) + og;

    f32x4 acc00 = {0,0,0,0}, acc01 = {0,0,0,0}, acc10 = {0,0,0,0}, acc11 = {0,0,0,0};
    #pragma unroll 4
    for (int ko = 0; ko < 8; ++ko) {
        f16x8 a0 = A0p[ko * 4];
        f16x8 a1 = A1p[ko * 4];
        f16x8 b0 = B0p[ko * 4];
        f16x8 b1 = B1p[ko * 4];
        acc00 = __builtin_amdgcn_mfma_f32_16x16x32_f16(a0, b0, acc00, 0, 0, 0);
        acc01 = __builtin_amdgcn_mfma_f32_16x16x32_f16(a0, b1, acc01, 0, 0, 0);
        acc10 = __builtin_amdgcn_mfma_f32_16x16x32_f16(a1, b0, acc10, 0, 0, 0);
        acc11 = __builtin_amdgcn_mfma_f32_16x16x32_f16(a1, b1, acc11, 0, 0, 0);
    }
    size_t rowBase = (size_t)(b * NN + m0 + og * 4) * TOTPOS;
    #pragma unroll
    for (int rr = 0; rr < 4; ++rr) {
        size_t ro0 = rowBase + (size_t)rr * TOTPOS;
        size_t ro1 = ro0 + (size_t)16 * TOTPOS;
        cws[ro0 + p0 + r]      = acc00[rr];
        cws[ro0 + p0 + 16 + r] = acc01[rr];
        cws[ro1 + p0 + r]      = acc10[rr];
        cws[ro1 + p0 + 16 + r] = acc11[rr];
    }
}

// -------------------- K4: upsample + MFMA conv1 + relu + MFMA conv2 + residual ------
// 8 out rows x 128 cols per block; grid x = 12 strips, y = B*N images.
// cT: f16 [ry 0..11][rx 0..131][ic 0..3]  (rows y0-2..y0+9, cols gx -2..129)
// hm: f16 [hy 0..9][hx 0..129][ic 0..15], XOR-swizzled: byte ^= (hx&0xC)<<2.
//     hy <-> y_img = y0+hy-1, hx <-> x_img = hx-1. Zero outside image (SAME pad).
// conv1: K=64 (9 taps x 4 ic, zero-padded), 2 MFMA per 16px tile.
// conv2: M=16px, K=160 (10 taps x 16 ic, tap9 zero), N=16 (col0 real), 5 MFMA/group.
__global__ __launch_bounds__(256, 2) void k_fuse(const float* __restrict__ cws,
                                                 const float* __restrict__ w1,
                                                 const float* __restrict__ w2,
                                                 float* __restrict__ out) {
    __shared__ _Float16 cT[12 * 132 * 4];      // 12672 B
    __shared__ _Float16 hm[10 * 130 * 16];     // 41600 B
    int img   = blockIdx.y;
    int strip = blockIdx.x;
    int y0 = strip * 8;
    int tid = threadIdx.x;
    int lane = tid & 63, wv = tid >> 6;
    int jj = lane & 15, og = lane >> 4;        // jj: A-row/pixel AND D-col/oc index
    int og2 = og >> 1, ogl = og & 1;
    const float* cb = cws + (size_t)img * TOTPOS;

    // ---- conv1 B fragments (K=64): k-map k = kk*4+ic (kk=tap 0..8, ic=k&3) ----
    f16x8 bf0, bf1;
    #pragma unroll
    for (int e = 0; e < 8; ++e) {
        int k0 = og * 8 + e;                   // 0..31 -> kk 0..7
        bf0[e] = (_Float16)w1[jj * 36 + (k0 & 3) * 9 + (k0 >> 2)];
        int k1 = 32 + og * 8 + e;              // kk 8..15, weight only kk==8
        int kk1 = k1 >> 2;
        bf1[e] = (kk1 <= 8) ? (_Float16)w1[jj * 36 + (k1 & 3) * 9 + kk1] : (_Float16)0.f;
    }
    // conv1 A-read offsets (f16 units): e<4 -> kk=2og, e>=4 -> kk=2og+1; plus kk=8 slot
    int ofs0, ofs1, ofs8;
    {
        int kk0 = 2 * og,     ky0 = kk0 / 3, kx0 = kk0 - ky0 * 3;
        int kk1 = 2 * og + 1, ky1 = kk1 / 3, kx1 = kk1 - ky1 * 3;
        ofs0 = (ky0 * 132 + kx0 + 1 + jj) * 4;
        ofs1 = (ky1 * 132 + kx1 + 1 + jj) * 4;
        ofs8 = (2 * 132 + 2 + 1 + jj) * 4;     // tap (2,2)
    }
    // ---- conv2 B fragments (K=160): k = tap*16+ic; tap = 2t+og2, ic = ogl*8+e ----
    f16x8 wB[5];
    #pragma unroll
    for (int t = 0; t < 5; ++t) {
        int tap = 2 * t + og2;
        #pragma unroll
        for (int e = 0; e < 8; ++e) {
            int ic = ogl * 8 + e;
            wB[t][e] = (jj == 0 && tap <= 8) ? (_Float16)w2[ic * 9 + tap] : (_Float16)0.f;
        }
    }
    // conv2 A-read byte offsets rel. to (oy*130 + x0)*32
    int aofs[5], jtx[5];
    #pragma unroll
    for (int t = 0; t < 5; ++t) {
        int tap = 2 * t + og2; if (tap > 8) tap = 8;
        int ty = tap / 3, tx = tap - ty * 3;
        aofs[t] = (ty * 130 + tx + jj) * 32 + ogl * 16;
        jtx[t] = jj + tx;
    }

    // ---- zero hm ----
    {
        uint4 z; z.x = z.y = z.z = z.w = 0u;
        uint4* hp = (uint4*)hm;
        for (int i = tid; i < (10 * 130 * 16 * 2) / 16; i += 256) hp[i] = z;
    }
    // ---- stage cT: level0 copy + bilinear upsample levels 1-3, SAME-pad zeros ----
    for (int i = tid; i < 12 * 132; i += 256) {
        int ry = i / 132, rx = i - ry * 132;
        int gy = y0 + ry - 2, gx = rx - 2;
        f16x4 vv = {(_Float16)0.f, (_Float16)0.f, (_Float16)0.f, (_Float16)0.f};
        if ((unsigned)gy < HH && (unsigned)gx < WW) {
            vv[0] = (_Float16)cb[gy * WW + gx];
            #pragma unroll
            for (int l = 1; l < 4; ++l) {
                int hl = HH >> l, wl = WW >> l;
                int lvlOff = (l == 1) ? 12288 : (l == 2) ? 15360 : 16128;
                float invk = (l == 1) ? 0.5f : (l == 2) ? 0.25f : 0.125f;
                float fy = (gy + 0.5f) * invk - 0.5f;
                float fx = (gx + 0.5f) * invk - 0.5f;
                float y0f = floorf(fy), x0f = floorf(fx);
                float ty = fy - y0f, tx = fx - x0f;
                int iy = (int)y0f, ix = (int)x0f;
                int y1 = min(iy + 1, hl - 1);
                iy = min(max(iy, 0), hl - 1);
                int x1 = min(ix + 1, wl - 1);
                ix = min(max(ix, 0), wl - 1);
                const float* base = cb + lvlOff;
                float v00 = base[iy * wl + ix], v01 = base[iy * wl + x1];
                float v10 = base[y1 * wl + ix], v11 = base[y1 * wl + x1];
                float v = (1.f - ty) * ((1.f - tx) * v00 + tx * v01)
                        +        ty  * ((1.f - tx) * v10 + tx * v11);
                vv[l] = (_Float16)v;
            }
        }
        *(f16x4*)&cT[i * 4] = vv;
    }
    __syncthreads();

    // ---- conv1: 80 M-tiles (hy 0..9, xg 0..7), 20 per wave, 2 MFMA each ----
    for (int t = wv * 20; t < wv * 20 + 20; ++t) {
        int hy = t >> 3, xg = t & 7;
        if ((unsigned)(y0 + hy - 1) >= (unsigned)HH) continue;   // row outside: stays 0
        int base = hy * 528 + xg * 64;
        f16x4 a00 = *(const f16x4*)&cT[base + ofs0];
        f16x4 a01 = *(const f16x4*)&cT[base + ofs1];
        f16x4 a8  = *(const f16x4*)&cT[base + ofs8];
        f16x8 A0, A1;
        #pragma unroll
        for (int e = 0; e < 4; ++e) {
            A0[e] = a00[e]; A0[4 + e] = a01[e];
            A1[e] = a8[e];  A1[4 + e] = a8[e];   // second half x zero weights
        }
        f32x4 acc = {0.f, 0.f, 0.f, 0.f};
        acc = __builtin_amdgcn_mfma_f32_16x16x32_f16(A0, bf0, acc, 0, 0, 0);
        acc = __builtin_amdgcn_mfma_f32_16x16x32_f16(A1, bf1, acc, 0, 0, 0);
        int xb = xg * 16 + og * 4;             // D row = og*4+rr -> pixel x
        #pragma unroll
        for (int rr = 0; rr < 4; ++rr) {
            int hx = xb + rr + 1;
            int byt = ((hy * 130 + hx) * 32 + jj * 2) ^ ((hx & 0xC) << 2);
            *(_Float16*)((char*)hm + byt) = (_Float16)fmaxf(acc[rr], 0.f);
        }
    }
    __syncthreads();

    // ---- conv2 via MFMA: 2 rows x 8 x-groups per wave ----
    #pragma unroll
    for (int rr2 = 0; rr2 < 2; ++rr2) {
        int oy = wv * 2 + rr2;
        int rowbase = oy * 130 * 32;
        for (int g = 0; g < 8; ++g) {
            int x0 = g * 16;
            int gbase = rowbase + x0 * 32;
            f32x4 acc = {0.f, 0.f, 0.f, 0.f};
            #pragma unroll
            for (int t = 0; t < 5; ++t) {
                int hxr = x0 + jtx[t];
                int byt = (gbase + aofs[t]) ^ ((hxr & 0xC) << 2);
                f16x8 av = *(const f16x8*)((const char*)hm + byt);
                acc = __builtin_amdgcn_mfma_f32_16x16x32_f16(av, wB[t], acc, 0, 0, 0);
            }
            if (jj == 0) {                      // D col 0 holds the real output
                int gy = y0 + oy;
                int xr = x0 + og * 4;           // D rows og*4..og*4+3
                const float4 res = *(const float4*)&cb[gy * WW + xr];
                float4 o;
                o.x = acc[0] + res.x; o.y = acc[1] + res.y;
                o.z = acc[2] + res.z; o.w = acc[3] + res.w;
                *(float4*)&out[(size_t)img * P0 + gy * WW + xr] = o;
            }
        }
    }
}

extern "C" void kernel_launch(void* const* d_in, const int* in_sizes, int n_in,
                              void* d_out, int out_size, void* d_ws, size_t ws_size,
                              hipStream_t stream) {
    const float* q  = (const float*)d_in[0];
    const float* f  = (const float*)d_in[1];
    const float* w1 = (const float*)d_in[2];
    const float* w2 = (const float*)d_in[3];
    float* out = (float*)d_out;

    float* cws = (float*)d_ws;                                    // B*N*TOTPOS fp32
    _Float16* flnT = (_Float16*)(cws + (size_t)BB * NN * TOTPOS); // B*TOTPOS*C f16
    _Float16* qn16 = flnT + (size_t)BB * TOTPOS * CC;             // B*N*C f16

    hipLaunchKernelGGL(k_qnorm, dim3(BB * NN / 4), dim3(256), 0, stream, q, qn16);
    hipLaunchKernelGGL(k_pool_norm, dim3(TOTPOS, BB), dim3(256), 0, stream, f, flnT);
    hipLaunchKernelGGL(k_gemm, dim3(255, 4, BB), dim3(256), 0, stream, qn16, flnT, cws);
    hipLaunchKernelGGL(k_fuse, dim3(12, BB * NN), dim3(256), 0, stream, cws, w1, w2, out);
}

// Round 7
// 439.331 us; speedup vs baseline: 1.2490x; 1.2490x over previous
//
#include <hip/hip_runtime.h>
#include <hip/hip_fp16.h>

#define BB 4
#define NN 256
#define CC 256
#define HH 96
#define WW 128
#define P0 (HH*WW)        // 12288
#define TOTPOS 16320      // 12288 + 3072 + 768 + 192 = 255*64

typedef _Float16 f16x4 __attribute__((ext_vector_type(4)));
typedef _Float16 f16x8 __attribute__((ext_vector_type(8)));
typedef _Float16 h2    __attribute__((ext_vector_type(2)));
typedef float    f32x4 __attribute__((ext_vector_type(4)));

#if defined(__has_builtin)
#if __has_builtin(__builtin_amdgcn_fdot2)
#define FDOT2(a,b,c) __builtin_amdgcn_fdot2((a),(b),(c),false)
#endif
#endif
#ifndef FDOT2
#define FDOT2(a,b,c) ((c) + (float)(a)[0]*(float)(b)[0] + (float)(a)[1]*(float)(b)[1])
#endif

// -------------------- K1: normalize q rows -> f16 --------------------
__global__ __launch_bounds__(256) void k_qnorm(const float* __restrict__ q,
                                               _Float16* __restrict__ qn16) {
    int wid = blockIdx.x * 4 + (threadIdx.x >> 6);   // (b*N+n)
    int lane = threadIdx.x & 63;
    const float4* src = (const float4*)(q + (size_t)wid * CC);
    float4 v = src[lane];
    float ss = v.x*v.x + v.y*v.y + v.z*v.z + v.w*v.w;
    #pragma unroll
    for (int off = 32; off > 0; off >>= 1) ss += __shfl_xor(ss, off, 64);
    float inv = 1.0f / fmaxf(sqrtf(ss), 1e-12f);
    f16x4 o;
    o[0] = (_Float16)(v.x*inv); o[1] = (_Float16)(v.y*inv);
    o[2] = (_Float16)(v.z*inv); o[3] = (_Float16)(v.w*inv);
    *(f16x4*)(qn16 + (size_t)wid * CC + lane * 4) = o;
}

// -------------------- K2: pool + channel-normalize -> f16 [b][p][c] --------------------
__global__ __launch_bounds__(256) void k_pool_norm(const float* __restrict__ f,
                                                   _Float16* __restrict__ flnT) {
    int b = blockIdx.y;
    int gp = blockIdx.x;
    int lvl, pos;
    if (gp < 12288)      { lvl = 0; pos = gp; }
    else if (gp < 15360) { lvl = 1; pos = gp - 12288; }
    else if (gp < 16128) { lvl = 2; pos = gp - 15360; }
    else                 { lvl = 3; pos = gp - 16128; }
    int k = 1 << lvl;
    int wl = WW >> lvl;
    int py = pos / wl, px = pos - py * wl;
    int c = threadIdx.x;
    int iy0 = py * k, ix0 = px * k;
    float sum = 0.f;
    for (int dy = 0; dy < k; ++dy)
        for (int dx = 0; dx < k; ++dx) {
            int ip = (iy0 + dy) * WW + ix0 + dx;
            sum += f[((size_t)b * P0 + ip) * CC + c];
        }
    float val = sum * (1.0f / (float)(k * k));
    float ss = val * val;
    #pragma unroll
    for (int off = 32; off > 0; off >>= 1) ss += __shfl_xor(ss, off, 64);
    __shared__ float red[4];
    __shared__ float s_inv;
    if ((threadIdx.x & 63) == 0) red[threadIdx.x >> 6] = ss;
    __syncthreads();
    if (threadIdx.x == 0) {
        float t = red[0] + red[1] + red[2] + red[3];
        s_inv = 1.0f / fmaxf(sqrtf(t), 1e-12f);
    }
    __syncthreads();
    flnT[((size_t)b * TOTPOS + gp) * CC + c] = (_Float16)(val * s_inv);
}

// -------------------- K3: MFMA GEMM (unchanged, proven) --------------------
__global__ __launch_bounds__(256, 4) void k_gemm(const _Float16* __restrict__ qn16,
                                                 const _Float16* __restrict__ flnT,
                                                 float* __restrict__ cws) {
    int b = blockIdx.z;
    int wv = threadIdx.x >> 6, lane = threadIdx.x & 63;
    int m0 = blockIdx.y * 64 + (wv >> 1) * 32;
    int p0 = blockIdx.x * 64 + (wv & 1) * 32;
    int r = lane & 15, og = lane >> 4;

    const f16x8* A0p = (const f16x8*)(qn16 + ((size_t)(b * NN + m0 + r)) * CC) + og;
    const f16x8* A1p = (const f16x8*)(qn16 + ((size_t)(b * NN + m0 + 16 + r)) * CC) + og;
    const f16x8* B0p = (const f16x8*)(flnT + ((size_t)b * TOTPOS + p0 + r) * CC) + og;
    const f16x8* B1p = (const f16x8*)(flnT + ((size_t)b * TOTPOS + p0 + 16 + r) * CC) + og;

    f32x4 acc00 = {0,0,0,0}, acc01 = {0,0,0,0}, acc10 = {0,0,0,0}, acc11 = {0,0,0,0};
    #pragma unroll 4
    for (int ko = 0; ko < 8; ++ko) {
        f16x8 a0 = A0p[ko * 4];
        f16x8 a1 = A1p[ko * 4];
        f16x8 b0 = B0p[ko * 4];
        f16x8 b1 = B1p[ko * 4];
        acc00 = __builtin_amdgcn_mfma_f32_16x16x32_f16(a0, b0, acc00, 0, 0, 0);
        acc01 = __builtin_amdgcn_mfma_f32_16x16x32_f16(a0, b1, acc01, 0, 0, 0);
        acc10 = __builtin_amdgcn_mfma_f32_16x16x32_f16(a1, b0, acc10, 0, 0, 0);
        acc11 = __builtin_amdgcn_mfma_f32_16x16x32_f16(a1, b1, acc11, 0, 0, 0);
    }
    size_t rowBase = (size_t)(b * NN + m0 + og * 4) * TOTPOS;
    #pragma unroll
    for (int rr = 0; rr < 4; ++rr) {
        size_t ro0 = rowBase + (size_t)rr * TOTPOS;
        size_t ro1 = ro0 + (size_t)16 * TOTPOS;
        cws[ro0 + p0 + r]      = acc00[rr];
        cws[ro0 + p0 + 16 + r] = acc01[rr];
        cws[ro1 + p0 + r]      = acc10[rr];
        cws[ro1 + p0 + 16 + r] = acc11[rr];
    }
}

// -------------------- K4: R4-proven structure, 512 threads for occupancy --------------------
// 8 out rows x 128 cols per block; grid x = 12 strips, y = B*N images. 512 thr = 8 waves;
// LDS 54.9 KB -> 2 blocks/CU -> 16 waves/CU (vs 8 at 256 thr): double latency hiding.
// cT: f16 [ry 0..11][rx 0..131][ic 0..3]; hm: __half [oc][hy 0..9][hx 0..131].
__global__ __launch_bounds__(512, 4) void k_fuse(const float* __restrict__ cws,
                                                 const float* __restrict__ w1,
                                                 const float* __restrict__ w2,
                                                 float* __restrict__ out) {
    __shared__ _Float16 cT[12 * 132 * 4];      // 12672 B
    __shared__ __half   hm[16 * 10 * 132];     // 42240 B
    __shared__ float    w2s[144];
    int img   = blockIdx.y;
    int strip = blockIdx.x;
    int y0 = strip * 8;
    int tid = threadIdx.x;
    int lane = tid & 63, wv = tid >> 6;        // 8 waves
    int oc = lane & 15, og = lane >> 4;
    const float* cb = cws + (size_t)img * TOTPOS;

    if (tid < 144) w2s[tid] = w2[tid];

    // conv1 B fragment (K=32, taps kk 0..7, ic fast) — proven R3/R4 convention
    f16x8 bf;
    #pragma unroll
    for (int e = 0; e < 8; ++e) {
        int k = og * 8 + e;
        bf[e] = (_Float16)w1[oc * 36 + (k & 3) * 9 + (k >> 2)];
    }
    h2 w22a, w22b;
    w22a[0] = (_Float16)w1[oc * 36 + 0 * 9 + 8];
    w22a[1] = (_Float16)w1[oc * 36 + 1 * 9 + 8];
    w22b[0] = (_Float16)w1[oc * 36 + 2 * 9 + 8];
    w22b[1] = (_Float16)w1[oc * 36 + 3 * 9 + 8];
    int ofs0, ofs1;
    {
        int kk0 = 2 * og,     ky0 = kk0 / 3, kx0 = kk0 - ky0 * 3;
        int kk1 = 2 * og + 1, ky1 = kk1 / 3, kx1 = kk1 - ky1 * 3;
        ofs0 = (ky0 * 132 + kx0 + 1 + oc) * 4;
        ofs1 = (ky1 * 132 + kx1 + 1 + oc) * 4;
    }
    // ---- zero hm ----
    {
        uint4 z; z.x = z.y = z.z = z.w = 0u;
        uint4* hp = (uint4*)hm;
        for (int i = tid; i < (16 * 10 * 132 * 2) / 16; i += 512) hp[i] = z;
    }
    // ---- stage cT ----
    for (int i = tid; i < 12 * 132; i += 512) {
        int ry = i / 132, rx = i - ry * 132;
        int gy = y0 + ry - 2, gx = rx - 2;
        f16x4 vv = {(_Float16)0.f, (_Float16)0.f, (_Float16)0.f, (_Float16)0.f};
        if ((unsigned)gy < HH && (unsigned)gx < WW) {
            vv[0] = (_Float16)cb[gy * WW + gx];
            #pragma unroll
            for (int l = 1; l < 4; ++l) {
                int hl = HH >> l, wl = WW >> l;
                int lvlOff = (l == 1) ? 12288 : (l == 2) ? 15360 : 16128;
                float invk = (l == 1) ? 0.5f : (l == 2) ? 0.25f : 0.125f;
                float fy = (gy + 0.5f) * invk - 0.5f;
                float fx = (gx + 0.5f) * invk - 0.5f;
                float y0f = floorf(fy), x0f = floorf(fx);
                float ty = fy - y0f, tx = fx - x0f;
                int iy = (int)y0f, ix = (int)x0f;
                int y1 = min(iy + 1, hl - 1);
                iy = min(max(iy, 0), hl - 1);
                int x1 = min(ix + 1, wl - 1);
                ix = min(max(ix, 0), wl - 1);
                const float* base = cb + lvlOff;
                float v00 = base[iy * wl + ix], v01 = base[iy * wl + x1];
                float v10 = base[y1 * wl + ix], v11 = base[y1 * wl + x1];
                float v = (1.f - ty) * ((1.f - tx) * v00 + tx * v01)
                        +        ty  * ((1.f - tx) * v10 + tx * v11);
                vv[l] = (_Float16)v;
            }
        }
        *(f16x4*)&cT[i * 4] = vv;
    }
    __syncthreads();

    // ---- conv1: 80 M-tiles, 10 per wave ----
    for (int t = wv * 10; t < wv * 10 + 10; ++t) {
        int hy = t >> 3, xg = t & 7;
        if ((unsigned)(y0 + hy - 1) >= (unsigned)HH) continue;
        int base = hy * 528 + xg * 64;
        f16x4 a0 = *(const f16x4*)&cT[base + ofs0];
        f16x4 a1 = *(const f16x4*)&cT[base + ofs1];
        f16x8 A;
        #pragma unroll
        for (int e = 0; e < 4; ++e) { A[e] = a0[e]; A[4 + e] = a1[e]; }
        f32x4 acc = {0.f, 0.f, 0.f, 0.f};
        acc = __builtin_amdgcn_mfma_f32_16x16x32_f16(A, bf, acc, 0, 0, 0);
        int xb = xg * 16 + og * 4;
        #pragma unroll
        for (int r = 0; r < 4; ++r) {
            int x = xb + r;
            f16x4 cv = *(const f16x4*)&cT[(hy + 2) * 528 + (x + 3) * 4];
            h2 lo, hi;
            lo[0] = cv[0]; lo[1] = cv[1];
            hi[0] = cv[2]; hi[1] = cv[3];
            float v = acc[r];
            v = FDOT2(lo, w22a, v);
            v = FDOT2(hi, w22b, v);
            hm[oc * 1320 + hy * 132 + (x + 1)] = __float2half(fmaxf(v, 0.f));
        }
    }
    __syncthreads();

    // ---- conv2 + residual: each thread 1x2 output px (lane-contiguous reads) ----
    int oy = tid >> 6, x2 = (tid & 63) * 2;
    float a2[2] = {0.f, 0.f};
    for (int ic = 0; ic < 16; ++ic) {
        float h[3][4];
        #pragma unroll
        for (int r = 0; r < 3; ++r)
            #pragma unroll
            for (int p = 0; p < 2; ++p) {
                __half2 t = *(const __half2*)&hm[ic * 1320 + (oy + r) * 132 + x2 + p * 2];
                float2 f2 = __half22float2(t);
                h[r][p*2] = f2.x; h[r][p*2+1] = f2.y;
            }
        #pragma unroll
        for (int ky = 0; ky < 3; ++ky)
            #pragma unroll
            for (int kx = 0; kx < 3; ++kx) {
                float w = w2s[ic * 9 + ky * 3 + kx];
                #pragma unroll
                for (int q = 0; q < 2; ++q)
                    a2[q] = fmaf(w, h[ky][q + kx], a2[q]);
            }
    }
    int gy = y0 + oy;
    const float2 res = *(const float2*)&cb[gy * WW + x2];
    float2 o;
    o.x = a2[0] + res.x; o.y = a2[1] + res.y;
    *(float2*)&out[(size_t)img * P0 + gy * WW + x2] = o;
}

extern "C" void kernel_launch(void* const* d_in, const int* in_sizes, int n_in,
                              void* d_out, int out_size, void* d_ws, size_t ws_size,
                              hipStream_t stream) {
    const float* q  = (const float*)d_in[0];
    const float* f  = (const float*)d_in[1];
    const float* w1 = (const float*)d_in[2];
    const float* w2 = (const float*)d_in[3];
    float* out = (float*)d_out;

    float* cws = (float*)d_ws;                                    // B*N*TOTPOS fp32
    _Float16* flnT = (_Float16*)(cws + (size_t)BB * NN * TOTPOS); // B*TOTPOS*C f16
    _Float16* qn16 = flnT + (size_t)BB * TOTPOS * CC;             // B*N*C f16

    hipLaunchKernelGGL(k_qnorm, dim3(BB * NN / 4), dim3(256), 0, stream, q, qn16);
    hipLaunchKernelGGL(k_pool_norm, dim3(TOTPOS, BB), dim3(256), 0, stream, f, flnT);
    hipLaunchKernelGGL(k_gemm, dim3(255, 4, BB), dim3(256), 0, stream, qn16, flnT, cws);
    hipLaunchKernelGGL(k_fuse, dim3(12, BB * NN), dim3(512), 0, stream, cws, w1, w2, out);
}

// Round 9
// 369.956 us; speedup vs baseline: 1.4832x; 1.1875x over previous
//
#include <hip/hip_runtime.h>
#include <hip/hip_fp16.h>

#define BB 4
#define NN 256
#define CC 256
#define HH 96
#define WW 128
#define P0 (HH*WW)        // 12288
#define TOTPOS 16320      // 12288 + 3072 + 768 + 192 = 255*64

typedef _Float16 f16x4 __attribute__((ext_vector_type(4)));
typedef _Float16 f16x8 __attribute__((ext_vector_type(8)));
typedef _Float16 h2    __attribute__((ext_vector_type(2)));
typedef float    f32x4 __attribute__((ext_vector_type(4)));

#if defined(__has_builtin)
#if __has_builtin(__builtin_amdgcn_fdot2)
#define FDOT2(a,b,c) __builtin_amdgcn_fdot2((a),(b),(c),false)
#endif
#endif
#ifndef FDOT2
#define FDOT2(a,b,c) ((c) + (float)(a)[0]*(float)(b)[0] + (float)(a)[1]*(float)(b)[1])
#endif

// hm swizzle — EXACT R5 HW-proven form: addr bits 4,5 keyed on hx bits 2,3.
__device__ __forceinline__ int hm_swz(int hx) {
    return (hx & 0xC) << 2;
}

// -------------------- K1: normalize q rows -> f16 --------------------
__global__ __launch_bounds__(256) void k_qnorm(const float* __restrict__ q,
                                               _Float16* __restrict__ qn16) {
    int wid = blockIdx.x * 4 + (threadIdx.x >> 6);   // (b*N+n)
    int lane = threadIdx.x & 63;
    const float4* src = (const float4*)(q + (size_t)wid * CC);
    float4 v = src[lane];
    float ss = v.x*v.x + v.y*v.y + v.z*v.z + v.w*v.w;
    #pragma unroll
    for (int off = 32; off > 0; off >>= 1) ss += __shfl_xor(ss, off, 64);
    float inv = 1.0f / fmaxf(sqrtf(ss), 1e-12f);
    f16x4 o;
    o[0] = (_Float16)(v.x*inv); o[1] = (_Float16)(v.y*inv);
    o[2] = (_Float16)(v.z*inv); o[3] = (_Float16)(v.w*inv);
    *(f16x4*)(qn16 + (size_t)wid * CC + lane * 4) = o;
}

// -------------------- K2: pool + channel-normalize -> f16 [b][p][c] --------------------
__global__ __launch_bounds__(256) void k_pool_norm(const float* __restrict__ f,
                                                   _Float16* __restrict__ flnT) {
    int b = blockIdx.y;
    int gp = blockIdx.x;
    int lvl, pos;
    if (gp < 12288)      { lvl = 0; pos = gp; }
    else if (gp < 15360) { lvl = 1; pos = gp - 12288; }
    else if (gp < 16128) { lvl = 2; pos = gp - 15360; }
    else                 { lvl = 3; pos = gp - 16128; }
    int k = 1 << lvl;
    int wl = WW >> lvl;
    int py = pos / wl, px = pos - py * wl;
    int c = threadIdx.x;
    int iy0 = py * k, ix0 = px * k;
    float sum = 0.f;
    for (int dy = 0; dy < k; ++dy)
        for (int dx = 0; dx < k; ++dx) {
            int ip = (iy0 + dy) * WW + ix0 + dx;
            sum += f[((size_t)b * P0 + ip) * CC + c];
        }
    float val = sum * (1.0f / (float)(k * k));
    float ss = val * val;
    #pragma unroll
    for (int off = 32; off > 0; off >>= 1) ss += __shfl_xor(ss, off, 64);
    __shared__ float red[4];
    __shared__ float s_inv;
    if ((threadIdx.x & 63) == 0) red[threadIdx.x >> 6] = ss;
    __syncthreads();
    if (threadIdx.x == 0) {
        float t = red[0] + red[1] + red[2] + red[3];
        s_inv = 1.0f / fmaxf(sqrtf(t), 1e-12f);
    }
    __syncthreads();
    flnT[((size_t)b * TOTPOS + gp) * CC + c] = (_Float16)(val * s_inv);
}

// -------------------- K3: MFMA GEMM (unchanged, proven) --------------------
__global__ __launch_bounds__(256, 4) void k_gemm(const _Float16* __restrict__ qn16,
                                                 const _Float16* __restrict__ flnT,
                                                 float* __restrict__ cws) {
    int b = blockIdx.z;
    int wv = threadIdx.x >> 6, lane = threadIdx.x & 63;
    int m0 = blockIdx.y * 64 + (wv >> 1) * 32;
    int p0 = blockIdx.x * 64 + (wv & 1) * 32;
    int r = lane & 15, og = lane >> 4;

    const f16x8* A0p = (const f16x8*)(qn16 + ((size_t)(b * NN + m0 + r)) * CC) + og;
    const f16x8* A1p = (const f16x8*)(qn16 + ((size_t)(b * NN + m0 + 16 + r)) * CC) + og;
    const f16x8* B0p = (const f16x8*)(flnT + ((size_t)b * TOTPOS + p0 + r) * CC) + og;
    const f16x8* B1p = (const f16x8*)(flnT + ((size_t)b * TOTPOS + p0 + 16 + r) * CC) + og;

    f32x4 acc00 = {0,0,0,0}, acc01 = {0,0,0,0}, acc10 = {0,0,0,0}, acc11 = {0,0,0,0};
    #pragma unroll 4
    for (int ko = 0; ko < 8; ++ko) {
        f16x8 a0 = A0p[ko * 4];
        f16x8 a1 = A1p[ko * 4];
        f16x8 b0 = B0p[ko * 4];
        f16x8 b1 = B1p[ko * 4];
        acc00 = __builtin_amdgcn_mfma_f32_16x16x32_f16(a0, b0, acc00, 0, 0, 0);
        acc01 = __builtin_amdgcn_mfma_f32_16x16x32_f16(a0, b1, acc01, 0, 0, 0);
        acc10 = __builtin_amdgcn_mfma_f32_16x16x32_f16(a1, b0, acc10, 0, 0, 0);
        acc11 = __builtin_amdgcn_mfma_f32_16x16x32_f16(a1, b1, acc11, 0, 0, 0);
    }
    size_t rowBase = (size_t)(b * NN + m0 + og * 4) * TOTPOS;
    #pragma unroll
    for (int rr = 0; rr < 4; ++rr) {
        size_t ro0 = rowBase + (size_t)rr * TOTPOS;
        size_t ro1 = ro0 + (size_t)16 * TOTPOS;
        cws[ro0 + p0 + r]      = acc00[rr];
        cws[ro0 + p0 + 16 + r] = acc01[rr];
        cws[ro1 + p0 + r]      = acc10[rr];
        cws[ro1 + p0 + 16 + r] = acc11[rr];
    }
}

// -------------------- K4: upsample + MFMA conv1 + relu + fdot2 conv2 + residual ------
// 8 out rows x 128 cols per block; 512 threads (8 waves); grid x = 12, y = B*N.
// cT: f16 [ry 0..11][rx 0..131][ic 0..3]
// hm: f16 [hy 0..9][hx 0..129][ic 0..15], byte ^= (hx&0xC)<<2  (R5 HW-proven swizzle).
__global__ __launch_bounds__(512, 4) void k_fuse(const float* __restrict__ cws,
                                                 const float* __restrict__ w1,
                                                 const float* __restrict__ w2,
                                                 float* __restrict__ out) {
    __shared__ _Float16 cT[12 * 132 * 4];      // 12672 B
    __shared__ _Float16 hm[10 * 130 * 16];     // 41600 B
    __shared__ h2 w2h2[72];                    // [tap 0..8][icpair 0..7]
    int img   = blockIdx.y;
    int strip = blockIdx.x;
    int y0 = strip * 8;
    int tid = threadIdx.x;
    int lane = tid & 63, wv = tid >> 6;        // 8 waves
    int oc = lane & 15, og = lane >> 4;
    const float* cb = cws + (size_t)img * TOTPOS;

    // w2 as h2 pairs along ic: w2h2[tap*8+j] = (w2[2j][tap], w2[2j+1][tap])
    if (tid < 72) {
        int tap = tid >> 3, j = tid & 7;
        h2 w; w[0] = (_Float16)w2[(2 * j) * 9 + tap];
        w[1] = (_Float16)w2[(2 * j + 1) * 9 + tap];
        w2h2[tid] = w;
    }

    // conv1 B fragment (K=32, taps kk 0..7, ic fast) — proven convention
    f16x8 bf;
    #pragma unroll
    for (int e = 0; e < 8; ++e) {
        int k = og * 8 + e;
        bf[e] = (_Float16)w1[oc * 36 + (k & 3) * 9 + (k >> 2)];
    }
    h2 w22a, w22b;
    w22a[0] = (_Float16)w1[oc * 36 + 0 * 9 + 8];
    w22a[1] = (_Float16)w1[oc * 36 + 1 * 9 + 8];
    w22b[0] = (_Float16)w1[oc * 36 + 2 * 9 + 8];
    w22b[1] = (_Float16)w1[oc * 36 + 3 * 9 + 8];
    int ofs0, ofs1;
    {
        int kk0 = 2 * og,     ky0 = kk0 / 3, kx0 = kk0 - ky0 * 3;
        int kk1 = 2 * og + 1, ky1 = kk1 / 3, kx1 = kk1 - ky1 * 3;
        ofs0 = (ky0 * 132 + kx0 + 1 + oc) * 4;
        ofs1 = (ky1 * 132 + kx1 + 1 + oc) * 4;
    }
    // ---- zero hm ----
    {
        uint4 z; z.x = z.y = z.z = z.w = 0u;
        uint4* hp = (uint4*)hm;
        for (int i = tid; i < (10 * 130 * 16 * 2) / 16; i += 512) hp[i] = z;
    }
    // ---- stage cT ----
    for (int i = tid; i < 12 * 132; i += 512) {
        int ry = i / 132, rx = i - ry * 132;
        int gy = y0 + ry - 2, gx = rx - 2;
        f16x4 vv = {(_Float16)0.f, (_Float16)0.f, (_Float16)0.f, (_Float16)0.f};
        if ((unsigned)gy < HH && (unsigned)gx < WW) {
            vv[0] = (_Float16)cb[gy * WW + gx];
            #pragma unroll
            for (int l = 1; l < 4; ++l) {
                int hl = HH >> l, wl = WW >> l;
                int lvlOff = (l == 1) ? 12288 : (l == 2) ? 15360 : 16128;
                float invk = (l == 1) ? 0.5f : (l == 2) ? 0.25f : 0.125f;
                float fy = (gy + 0.5f) * invk - 0.5f;
                float fx = (gx + 0.5f) * invk - 0.5f;
                float y0f = floorf(fy), x0f = floorf(fx);
                float ty = fy - y0f, tx = fx - x0f;
                int iy = (int)y0f, ix = (int)x0f;
                int y1 = min(iy + 1, hl - 1);
                iy = min(max(iy, 0), hl - 1);
                int x1 = min(ix + 1, wl - 1);
                ix = min(max(ix, 0), wl - 1);
                const float* base = cb + lvlOff;
                float v00 = base[iy * wl + ix], v01 = base[iy * wl + x1];
                float v10 = base[y1 * wl + ix], v11 = base[y1 * wl + x1];
                float v = (1.f - ty) * ((1.f - tx) * v00 + tx * v01)
                        +        ty  * ((1.f - tx) * v10 + tx * v11);
                vv[l] = (_Float16)v;
            }
        }
        *(f16x4*)&cT[i * 4] = vv;
    }
    __syncthreads();

    // ---- conv1: 80 M-tiles, 10 per wave; store to hm[hy][hx][ic] swizzled ----
    for (int t = wv * 10; t < wv * 10 + 10; ++t) {
        int hy = t >> 3, xg = t & 7;
        if ((unsigned)(y0 + hy - 1) >= (unsigned)HH) continue;
        int base = hy * 528 + xg * 64;
        f16x4 a0 = *(const f16x4*)&cT[base + ofs0];
        f16x4 a1 = *(const f16x4*)&cT[base + ofs1];
        f16x8 A;
        #pragma unroll
        for (int e = 0; e < 4; ++e) { A[e] = a0[e]; A[4 + e] = a1[e]; }
        f32x4 acc = {0.f, 0.f, 0.f, 0.f};
        acc = __builtin_amdgcn_mfma_f32_16x16x32_f16(A, bf, acc, 0, 0, 0);
        int xb = xg * 16 + og * 4;
        #pragma unroll
        for (int r = 0; r < 4; ++r) {
            int x = xb + r;
            f16x4 cv = *(const f16x4*)&cT[(hy + 2) * 528 + (x + 3) * 4];
            h2 lo, hi;
            lo[0] = cv[0]; lo[1] = cv[1];
            hi[0] = cv[2]; hi[1] = cv[3];
            float v = acc[r];
            v = FDOT2(lo, w22a, v);
            v = FDOT2(hi, w22b, v);
            int hx = x + 1;
            int byt = ((hy * 130 + hx) * 32 + oc * 2) ^ hm_swz(hx);
            *(_Float16*)((char*)hm + byt) = (_Float16)fmaxf(v, 0.f);
        }
    }
    __syncthreads();

    // ---- conv2 via fdot2 on f16x8: each thread 1x2 output px ----
    int oy = wv, x2 = lane * 2;
    float a2[2] = {0.f, 0.f};
    #pragma unroll
    for (int r = 0; r < 3; ++r) {
        int hy = oy + r;
        h2 wrow[3][8];
        #pragma unroll
        for (int kx = 0; kx < 3; ++kx)
            #pragma unroll
            for (int j = 0; j < 8; ++j) wrow[kx][j] = w2h2[(r * 3 + kx) * 8 + j];
        f16x8 d[4][2];
        #pragma unroll
        for (int c4 = 0; c4 < 4; ++c4) {
            int hx = x2 + c4;
            int bas = (hy * 130 + hx) * 32;
            int sw = hm_swz(hx);
            d[c4][0] = *(const f16x8*)((const char*)hm + ((bas) ^ sw));
            d[c4][1] = *(const f16x8*)((const char*)hm + ((bas + 16) ^ sw));
        }
        #pragma unroll
        for (int q = 0; q < 2; ++q)
            #pragma unroll
            for (int kx = 0; kx < 3; ++kx) {
                f16x8 lo = d[q + kx][0];
                f16x8 hi = d[q + kx][1];
                #pragma unroll
                for (int j = 0; j < 4; ++j) {
                    h2 p0; p0[0] = lo[2 * j]; p0[1] = lo[2 * j + 1];
                    a2[q] = FDOT2(p0, wrow[kx][j], a2[q]);
                    h2 p1; p1[0] = hi[2 * j]; p1[1] = hi[2 * j + 1];
                    a2[q] = FDOT2(p1, wrow[kx][j + 4], a2[q]);
                }
            }
    }
    int gy = y0 + oy;
    const float2 res = *(const float2*)&cb[gy * WW + x2];
    float2 o;
    o.x = a2[0] + res.x; o.y = a2[1] + res.y;
    *(float2*)&out[(size_t)img * P0 + gy * WW + x2] = o;
}

extern "C" void kernel_launch(void* const* d_in, const int* in_sizes, int n_in,
                              void* d_out, int out_size, void* d_ws, size_t ws_size,
                              hipStream_t stream) {
    const float* q  = (const float*)d_in[0];
    const float* f  = (const float*)d_in[1];
    const float* w1 = (const float*)d_in[2];
    const float* w2 = (const float*)d_in[3];
    float* out = (float*)d_out;

    float* cws = (float*)d_ws;                                    // B*N*TOTPOS fp32
    _Float16* flnT = (_Float16*)(cws + (size_t)BB * NN * TOTPOS); // B*TOTPOS*C f16
    _Float16* qn16 = flnT + (size_t)BB * TOTPOS * CC;             // B*N*C f16

    hipLaunchKernelGGL(k_qnorm, dim3(BB * NN / 4), dim3(256), 0, stream, q, qn16);
    hipLaunchKernelGGL(k_pool_norm, dim3(TOTPOS, BB), dim3(256), 0, stream, f, flnT);
    hipLaunchKernelGGL(k_gemm, dim3(255, 4, BB), dim3(256), 0, stream, qn16, flnT, cws);
    hipLaunchKernelGGL(k_fuse, dim3(12, BB * NN), dim3(512), 0, stream, cws, w1, w2, out);
}

// Round 10
// 359.180 us; speedup vs baseline: 1.5277x; 1.0300x over previous
//
#include <hip/hip_runtime.h>
#include <hip/hip_fp16.h>

#define BB 4
#define NN 256
#define CC 256
#define HH 96
#define WW 128
#define P0 (HH*WW)        // 12288
#define TOTPOS 16320      // 12288 + 3072 + 768 + 192 = 255*64

typedef _Float16 f16x4 __attribute__((ext_vector_type(4)));
typedef _Float16 f16x8 __attribute__((ext_vector_type(8)));
typedef _Float16 h2    __attribute__((ext_vector_type(2)));
typedef float    f32x4 __attribute__((ext_vector_type(4)));

#if defined(__has_builtin)
#if __has_builtin(__builtin_amdgcn_fdot2)
#define FDOT2(a,b,c) __builtin_amdgcn_fdot2((a),(b),(c),false)
#endif
#endif
#ifndef FDOT2
#define FDOT2(a,b,c) ((c) + (float)(a)[0]*(float)(b)[0] + (float)(a)[1]*(float)(b)[1])
#endif

// hm swizzle — HW-proven (R5/R8): addr bits 4,5 keyed on hx bits 2,3.
__device__ __forceinline__ int hm_swz(int hx) {
    return (hx & 0xC) << 2;
}

// -------------------- K1: normalize q rows -> f16 --------------------
__global__ __launch_bounds__(256) void k_qnorm(const float* __restrict__ q,
                                               _Float16* __restrict__ qn16) {
    int wid = blockIdx.x * 4 + (threadIdx.x >> 6);   // (b*N+n)
    int lane = threadIdx.x & 63;
    const float4* src = (const float4*)(q + (size_t)wid * CC);
    float4 v = src[lane];
    float ss = v.x*v.x + v.y*v.y + v.z*v.z + v.w*v.w;
    #pragma unroll
    for (int off = 32; off > 0; off >>= 1) ss += __shfl_xor(ss, off, 64);
    float inv = 1.0f / fmaxf(sqrtf(ss), 1e-12f);
    f16x4 o;
    o[0] = (_Float16)(v.x*inv); o[1] = (_Float16)(v.y*inv);
    o[2] = (_Float16)(v.z*inv); o[3] = (_Float16)(v.w*inv);
    *(f16x4*)(qn16 + (size_t)wid * CC + lane * 4) = o;
}

// -------------------- K2: pool + channel-normalize -> f16 [b][p][c] --------------------
__global__ __launch_bounds__(256) void k_pool_norm(const float* __restrict__ f,
                                                   _Float16* __restrict__ flnT) {
    int b = blockIdx.y;
    int gp = blockIdx.x;
    int lvl, pos;
    if (gp < 12288)      { lvl = 0; pos = gp; }
    else if (gp < 15360) { lvl = 1; pos = gp - 12288; }
    else if (gp < 16128) { lvl = 2; pos = gp - 15360; }
    else                 { lvl = 3; pos = gp - 16128; }
    int k = 1 << lvl;
    int wl = WW >> lvl;
    int py = pos / wl, px = pos - py * wl;
    int c = threadIdx.x;
    int iy0 = py * k, ix0 = px * k;
    float sum = 0.f;
    for (int dy = 0; dy < k; ++dy)
        for (int dx = 0; dx < k; ++dx) {
            int ip = (iy0 + dy) * WW + ix0 + dx;
            sum += f[((size_t)b * P0 + ip) * CC + c];
        }
    float val = sum * (1.0f / (float)(k * k));
    float ss = val * val;
    #pragma unroll
    for (int off = 32; off > 0; off >>= 1) ss += __shfl_xor(ss, off, 64);
    __shared__ float red[4];
    __shared__ float s_inv;
    if ((threadIdx.x & 63) == 0) red[threadIdx.x >> 6] = ss;
    __syncthreads();
    if (threadIdx.x == 0) {
        float t = red[0] + red[1] + red[2] + red[3];
        s_inv = 1.0f / fmaxf(sqrtf(t), 1e-12f);
    }
    __syncthreads();
    flnT[((size_t)b * TOTPOS + gp) * CC + c] = (_Float16)(val * s_inv);
}

// -------------------- K3: MFMA GEMM (unchanged, proven) --------------------
__global__ __launch_bounds__(256, 4) void k_gemm(const _Float16* __restrict__ qn16,
                                                 const _Float16* __restrict__ flnT,
                                                 float* __restrict__ cws) {
    int b = blockIdx.z;
    int wv = threadIdx.x >> 6, lane = threadIdx.x & 63;
    int m0 = blockIdx.y * 64 + (wv >> 1) * 32;
    int p0 = blockIdx.x * 64 + (wv & 1) * 32;
    int r = lane & 15, og = lane >> 4;

    const f16x8* A0p = (const f16x8*)(qn16 + ((size_t)(b * NN + m0 + r)) * CC) + og;
    const f16x8* A1p = (const f16x8*)(qn16 + ((size_t)(b * NN + m0 + 16 + r)) * CC) + og;
    const f16x8* B0p = (const f16x8*)(flnT + ((size_t)b * TOTPOS + p0 + r) * CC) + og;
    const f16x8* B1p = (const f16x8*)(flnT + ((size_t)b * TOTPOS + p0 + 16 + r) * CC) + og;

    f32x4 acc00 = {0,0,0,0}, acc01 = {0,0,0,0}, acc10 = {0,0,0,0}, acc11 = {0,0,0,0};
    #pragma unroll 4
    for (int ko = 0; ko < 8; ++ko) {
        f16x8 a0 = A0p[ko * 4];
        f16x8 a1 = A1p[ko * 4];
        f16x8 b0 = B0p[ko * 4];
        f16x8 b1 = B1p[ko * 4];
        acc00 = __builtin_amdgcn_mfma_f32_16x16x32_f16(a0, b0, acc00, 0, 0, 0);
        acc01 = __builtin_amdgcn_mfma_f32_16x16x32_f16(a0, b1, acc01, 0, 0, 0);
        acc10 = __builtin_amdgcn_mfma_f32_16x16x32_f16(a1, b0, acc10, 0, 0, 0);
        acc11 = __builtin_amdgcn_mfma_f32_16x16x32_f16(a1, b1, acc11, 0, 0, 0);
    }
    size_t rowBase = (size_t)(b * NN + m0 + og * 4) * TOTPOS;
    #pragma unroll
    for (int rr = 0; rr < 4; ++rr) {
        size_t ro0 = rowBase + (size_t)rr * TOTPOS;
        size_t ro1 = ro0 + (size_t)16 * TOTPOS;
        cws[ro0 + p0 + r]      = acc00[rr];
        cws[ro0 + p0 + 16 + r] = acc01[rr];
        cws[ro1 + p0 + r]      = acc10[rr];
        cws[ro1 + p0 + 16 + r] = acc11[rr];
    }
}

// -------------------- K4: LUT staging + K=64 MFMA conv1 + relu + fdot2 conv2 + residual ------
// 8 out rows x 128 cols per block; 512 threads (8 waves); grid x = 12, y = B*N.
// cT: f16 [ry 0..11][rx 0..131][ic 0..3]
// hm: f16 [hy 0..9][hx 0..129][ic 0..15], byte ^= (hx&0xC)<<2  (HW-proven swizzle).
__global__ __launch_bounds__(512, 4) void k_fuse(const float* __restrict__ cws,
                                                 const float* __restrict__ w1,
                                                 const float* __restrict__ w2,
                                                 float* __restrict__ out) {
    __shared__ _Float16 cT[12 * 132 * 4];      // 12672 B
    __shared__ _Float16 hm[10 * 130 * 16];     // 41600 B
    __shared__ h2 w2h2[72];                    // [tap 0..8][icpair 0..7]
    __shared__ int   xt01[3][132];             // x0 | x1<<16 (per level)
    __shared__ float xttx[3][132];
    __shared__ int   yt01[3][12];
    __shared__ float ytty[3][12];
    int img   = blockIdx.y;
    int strip = blockIdx.x;
    int y0 = strip * 8;
    int tid = threadIdx.x;
    int lane = tid & 63, wv = tid >> 6;        // 8 waves
    int oc = lane & 15, og = lane >> 4;
    const float* cb = cws + (size_t)img * TOTPOS;

    // w2 as h2 pairs along ic
    if (tid < 72) {
        int tap = tid >> 3, j = tid & 7;
        h2 w; w[0] = (_Float16)w2[(2 * j) * 9 + tap];
        w[1] = (_Float16)w2[(2 * j + 1) * 9 + tap];
        w2h2[tid] = w;
    }
    // ---- bilinear LUTs (position-only arithmetic, hoisted out of staging) ----
    for (int i = tid; i < 3 * 132; i += 512) {
        int l = i / 132 + 1, rx = i - (l - 1) * 132;
        int wl = WW >> l;
        float invk = (l == 1) ? 0.5f : (l == 2) ? 0.25f : 0.125f;
        float fx = ((rx - 2) + 0.5f) * invk - 0.5f;
        float x0f = floorf(fx);
        int ix = (int)x0f;
        int x1 = min(ix + 1, wl - 1); if (x1 < 0) x1 = 0;
        int x0 = min(max(ix, 0), wl - 1);
        xt01[l - 1][rx] = x0 | (x1 << 16);
        xttx[l - 1][rx] = fx - x0f;
    }
    if (tid < 36) {
        int l = tid / 12 + 1, ry = tid - (l - 1) * 12;
        int hl = HH >> l;
        float invk = (l == 1) ? 0.5f : (l == 2) ? 0.25f : 0.125f;
        float fy = ((y0 + ry - 2) + 0.5f) * invk - 0.5f;
        float y0f = floorf(fy);
        int iy = (int)y0f;
        int y1 = min(iy + 1, hl - 1); if (y1 < 0) y1 = 0;
        int yc = min(max(iy, 0), hl - 1);
        yt01[l - 1][ry] = yc | (y1 << 16);
        ytty[l - 1][ry] = fy - y0f;
    }

    // conv1 B fragments (K=64, taps kk 0..8 zero-padded to 16) — R5 HW-proven
    f16x8 bf0, bf1;
    #pragma unroll
    for (int e = 0; e < 8; ++e) {
        int k0 = og * 8 + e;                   // kk 0..7
        bf0[e] = (_Float16)w1[oc * 36 + (k0 & 3) * 9 + (k0 >> 2)];
        int k1 = 32 + og * 8 + e;              // kk 8..15, weight only kk==8
        int kk1 = k1 >> 2;
        bf1[e] = (kk1 <= 8) ? (_Float16)w1[oc * 36 + (k1 & 3) * 9 + kk1] : (_Float16)0.f;
    }
    int ofs0, ofs1, ofs8;
    {
        int kk0 = 2 * og,     ky0 = kk0 / 3, kx0 = kk0 - ky0 * 3;
        int kk1 = 2 * og + 1, ky1 = kk1 / 3, kx1 = kk1 - ky1 * 3;
        ofs0 = (ky0 * 132 + kx0 + 1 + oc) * 4;
        ofs1 = (ky1 * 132 + kx1 + 1 + oc) * 4;
        ofs8 = (2 * 132 + 2 + 1 + oc) * 4;     // tap (2,2)
    }
    // ---- zero hm ----
    {
        uint4 z; z.x = z.y = z.z = z.w = 0u;
        uint4* hp = (uint4*)hm;
        for (int i = tid; i < (10 * 130 * 16 * 2) / 16; i += 512) hp[i] = z;
    }
    __syncthreads();   // tables ready

    // ---- stage cT via LUTs ----
    for (int i = tid; i < 12 * 132; i += 512) {
        int ry = i / 132, rx = i - ry * 132;
        int gy = y0 + ry - 2, gx = rx - 2;
        f16x4 vv = {(_Float16)0.f, (_Float16)0.f, (_Float16)0.f, (_Float16)0.f};
        if ((unsigned)gy < HH && (unsigned)gx < WW) {
            vv[0] = (_Float16)cb[gy * WW + gx];
            #pragma unroll
            for (int l = 1; l < 4; ++l) {
                int wl = WW >> l;
                int lvlOff = (l == 1) ? 12288 : (l == 2) ? 15360 : 16128;
                int p01 = xt01[l - 1][rx];
                float tx = xttx[l - 1][rx];
                int q01 = yt01[l - 1][ry];
                float ty = ytty[l - 1][ry];
                int x0 = p01 & 0xFFFF, x1 = p01 >> 16;
                int ya = q01 & 0xFFFF, yb = q01 >> 16;
                const float* r0 = cb + lvlOff + ya * wl;
                const float* r1 = cb + lvlOff + yb * wl;
                float v00 = r0[x0], v01 = r0[x1];
                float v10 = r1[x0], v11 = r1[x1];
                float top = v00 + tx * (v01 - v00);
                float bot = v10 + tx * (v11 - v10);
                vv[l] = (_Float16)(top + ty * (bot - top));
            }
        }
        *(f16x4*)&cT[i * 4] = vv;
    }
    __syncthreads();

    // ---- conv1: 80 M-tiles, 10 per wave, K=64 double-MFMA ----
    for (int t = wv * 10; t < wv * 10 + 10; ++t) {
        int hy = t >> 3, xg = t & 7;
        if ((unsigned)(y0 + hy - 1) >= (unsigned)HH) continue;
        int base = hy * 528 + xg * 64;
        f16x4 a00 = *(const f16x4*)&cT[base + ofs0];
        f16x4 a01 = *(const f16x4*)&cT[base + ofs1];
        f16x4 a8  = *(const f16x4*)&cT[base + ofs8];
        f16x8 A0, A1;
        #pragma unroll
        for (int e = 0; e < 4; ++e) {
            A0[e] = a00[e]; A0[4 + e] = a01[e];
            A1[e] = a8[e];  A1[4 + e] = a8[e];   // second half x zero weights
        }
        f32x4 acc = {0.f, 0.f, 0.f, 0.f};
        acc = __builtin_amdgcn_mfma_f32_16x16x32_f16(A0, bf0, acc, 0, 0, 0);
        acc = __builtin_amdgcn_mfma_f32_16x16x32_f16(A1, bf1, acc, 0, 0, 0);
        int xb = xg * 16 + og * 4;
        #pragma unroll
        for (int r = 0; r < 4; ++r) {
            int hx = xb + r + 1;
            int byt = ((hy * 130 + hx) * 32 + oc * 2) ^ hm_swz(hx);
            *(_Float16*)((char*)hm + byt) = (_Float16)fmaxf(acc[r], 0.f);
        }
    }
    __syncthreads();

    // ---- conv2 via fdot2 on f16x8: each thread 1x2 output px (HW-proven R8) ----
    int oy = wv, x2 = lane * 2;
    float a2[2] = {0.f, 0.f};
    #pragma unroll
    for (int r = 0; r < 3; ++r) {
        int hy = oy + r;
        h2 wrow[3][8];
        #pragma unroll
        for (int kx = 0; kx < 3; ++kx)
            #pragma unroll
            for (int j = 0; j < 8; ++j) wrow[kx][j] = w2h2[(r * 3 + kx) * 8 + j];
        f16x8 d[4][2];
        #pragma unroll
        for (int c4 = 0; c4 < 4; ++c4) {
            int hx = x2 + c4;
            int bas = (hy * 130 + hx) * 32;
            int sw = hm_swz(hx);
            d[c4][0] = *(const f16x8*)((const char*)hm + ((bas) ^ sw));
            d[c4][1] = *(const f16x8*)((const char*)hm + ((bas + 16) ^ sw));
        }
        #pragma unroll
        for (int q = 0; q < 2; ++q)
            #pragma unroll
            for (int kx = 0; kx < 3; ++kx) {
                f16x8 lo = d[q + kx][0];
                f16x8 hi = d[q + kx][1];
                #pragma unroll
                for (int j = 0; j < 4; ++j) {
                    h2 p0; p0[0] = lo[2 * j]; p0[1] = lo[2 * j + 1];
                    a2[q] = FDOT2(p0, wrow[kx][j], a2[q]);
                    h2 p1; p1[0] = hi[2 * j]; p1[1] = hi[2 * j + 1];
                    a2[q] = FDOT2(p1, wrow[kx][j + 4], a2[q]);
                }
            }
    }
    int gy = y0 + oy;
    const float2 res = *(const float2*)&cb[gy * WW + x2];
    float2 o;
    o.x = a2[0] + res.x; o.y = a2[1] + res.y;
    *(float2*)&out[(size_t)img * P0 + gy * WW + x2] = o;
}

extern "C" void kernel_launch(void* const* d_in, const int* in_sizes, int n_in,
                              void* d_out, int out_size, void* d_ws, size_t ws_size,
                              hipStream_t stream) {
    const float* q  = (const float*)d_in[0];
    const float* f  = (const float*)d_in[1];
    const float* w1 = (const float*)d_in[2];
    const float* w2 = (const float*)d_in[3];
    float* out = (float*)d_out;

    float* cws = (float*)d_ws;                                    // B*N*TOTPOS fp32
    _Float16* flnT = (_Float16*)(cws + (size_t)BB * NN * TOTPOS); // B*TOTPOS*C f16
    _Float16* qn16 = flnT + (size_t)BB * TOTPOS * CC;             // B*N*C f16

    hipLaunchKernelGGL(k_qnorm, dim3(BB * NN / 4), dim3(256), 0, stream, q, qn16);
    hipLaunchKernelGGL(k_pool_norm, dim3(TOTPOS, BB), dim3(256), 0, stream, f, flnT);
    hipLaunchKernelGGL(k_gemm, dim3(255, 4, BB), dim3(256), 0, stream, qn16, flnT, cws);
    hipLaunchKernelGGL(k_fuse, dim3(12, BB * NN), dim3(512), 0, stream, cws, w1, w2, out);
}